// Round 1
// baseline (467.143 us; speedup 1.0000x reference)
//
#include <hip/hip_runtime.h>
#include <math.h>

#define NN 20480
#define NE 327680
#define NBATCH 16

__device__ __forceinline__ void atomAddF(float* p, float v) {
  unsafeAtomicAdd(p, v);   // global_atomic_add_f32, device scope
}

// ---------------- degree (graph fixed across layers: compute once) ----------
__global__ void deg_kernel(const int* __restrict__ dst, float* __restrict__ deg) {
  int e = blockIdx.x * blockDim.x + threadIdx.x;
  if (e < NE) atomAddF(&deg[dst[e]], 1.0f);
}

// ---------------- edge kernel, cout==8 layers (L1..L3) ----------------------
// Mapping: 8 edges per wave, lane = (e_sub<<3)|o. Per-lane o fixed -> hoist
// the 6 affine params per i into registers; emb stays in LDS with +1/type
// padding (stride cin*8 is 0 mod 32 -> would be 8-way bank conflict).
template<int CIN>
__global__ __launch_bounds__(256) void edge_small(
    const int* __restrict__ src, const int* __restrict__ dst,
    const int* __restrict__ etype, const float* __restrict__ eattr,
    const float* __restrict__ h_in,
    const float* __restrict__ emb, const float* __restrict__ wh,
    const float* __restrict__ bh, const float* __restrict__ wg,
    const float* __restrict__ bg, float* __restrict__ agg) {
  constexpr int D = CIN * 8;
  constexpr int STRIDE = D + 1;            // bank-conflict pad
  __shared__ float semb[36 * STRIDE];
  for (int idx = threadIdx.x; idx < 36 * D; idx += 256) {
    int t = idx / D, io = idx - t * D;
    semb[t * STRIDE + io] = emb[idx];
  }
  int lane = threadIdx.x & 63;
  int o = lane & 7;
  float rwh0[CIN], rwh1[CIN], rbh[CIN], rwg0[CIN], rwg1[CIN], rbg[CIN];
#pragma unroll
  for (int i = 0; i < CIN; i++) {
    int io = i * 8 + o;
    rwh0[i] = wh[io]; rwh1[i] = wh[D + io]; rbh[i] = bh[io];
    rwg0[i] = wg[io]; rwg1[i] = wg[D + io]; rbg[i] = bg[io];
  }
  __syncthreads();
  int gw = blockIdx.x * 4 + (threadIdx.x >> 6);
  int TW = gridDim.x * 4;
  int esub = lane >> 3;
  for (int g = gw; g < NE / 8; g += TW) {
    int e = g * 8 + esub;
    int s = src[e], d = dst[e], t = etype[e];
    float ef0 = eattr[2 * e], ef1 = eattr[2 * e + 1];
    const float* st = &semb[t * STRIDE + o];
    const float* hp = &h_in[s * CIN];
    float msg = 0.f;
#pragma unroll
    for (int i = 0; i < CIN; i++) {
      float hval = fmaf(ef0, rwh0[i], fmaf(ef1, rwh1[i], rbh[i]));
      float gval = fmaf(ef0, rwg0[i], fmaf(ef1, rwg1[i], rbg[i]));
      float w = fmaxf(fmaf(st[i * 8], hval, gval), 0.f);
      msg = fmaf(hp[i], w, msg);
    }
    atomAddF(&agg[d * 8 + o], msg);
  }
}

// ---------------- edge kernel, layer 4 (cin=8, cout=64) ---------------------
// One wave per edge, lane = output channel. Edge scalars forced wave-uniform
// (readfirstlane) so src/dst/type/attr and the h row become s_loads.
// emb4 (36*512 floats = 73.7KB) in LDS: ds_read_b32, lanes consecutive
// -> 2 lanes/bank = free.
__global__ __launch_bounds__(256) void edge_l4(
    const int* __restrict__ src, const int* __restrict__ dst,
    const int* __restrict__ etype, const float* __restrict__ eattr,
    const float* __restrict__ h_in,
    const float* __restrict__ emb, const float* __restrict__ wh,
    const float* __restrict__ bh, const float* __restrict__ wg,
    const float* __restrict__ bg, float* __restrict__ agg) {
  __shared__ float semb[36 * 512];
  for (int idx = threadIdx.x; idx < 36 * 512; idx += 256) semb[idx] = emb[idx];
  int lane = threadIdx.x & 63;
  float rwh0[8], rwh1[8], rbh[8], rwg0[8], rwg1[8], rbg[8];
#pragma unroll
  for (int i = 0; i < 8; i++) {
    int io = i * 64 + lane;
    rwh0[i] = wh[io]; rwh1[i] = wh[512 + io]; rbh[i] = bh[io];
    rwg0[i] = wg[io]; rwg1[i] = wg[512 + io]; rbg[i] = bg[io];
  }
  __syncthreads();
  int gw = blockIdx.x * 4 + (threadIdx.x >> 6);
  int TW = gridDim.x * 4;
  for (int e0 = gw; e0 < NE; e0 += TW) {
    int e = __builtin_amdgcn_readfirstlane(e0);   // wave-uniform -> s_loads
    int s = src[e], d = dst[e], t = etype[e];
    float ef0 = eattr[2 * e], ef1 = eattr[2 * e + 1];
    const float* hp = &h_in[s * 8];
    float hv[8];
#pragma unroll
    for (int i = 0; i < 8; i++) hv[i] = hp[i];
    const float* st = &semb[t * 512 + lane];
    float msg = 0.f;
#pragma unroll
    for (int i = 0; i < 8; i++) {
      float hval = fmaf(ef0, rwh0[i], fmaf(ef1, rwh1[i], rbh[i]));
      float gval = fmaf(ef0, rwg0[i], fmaf(ef1, rwg1[i], rbg[i]));
      float w = fmaxf(fmaf(st[i * 64], hval, gval), 0.f);
      msg = fmaf(hv[i], w, msg);
    }
    atomAddF(&agg[d * 64 + lane], msg);
  }
}

// ---------------- node update: mean-agg + root matmul + bias + relu ---------
template<int CIN, int COUT>
__global__ void node_kernel(const float* __restrict__ agg,
                            const float* __restrict__ deg,
                            const float* __restrict__ h_in,
                            const float* __restrict__ root,
                            const float* __restrict__ bias,
                            float* __restrict__ h_out) {
  int idx = blockIdx.x * blockDim.x + threadIdx.x;
  if (idx >= NN * COUT) return;
  int n = idx / COUT, o = idx - n * COUT;
  float acc = bias[o];
#pragma unroll
  for (int i = 0; i < CIN; i++)
    acc = fmaf(h_in[n * CIN + i], root[i * COUT + o], acc);
  acc += agg[idx] / fmaxf(deg[n], 1.0f);
  h_out[idx] = fmaxf(acc, 0.f);
}

// ---------------- gated pooling + classifier + sigmoid ----------------------
// batch = arange(N)//1280 (contiguous), so block b owns nodes [b*1280,(b+1)*1280)
__global__ __launch_bounds__(256) void pool_kernel(
    const float* __restrict__ h4, const int* __restrict__ ct,
    const float* __restrict__ clf_w, const float* __restrict__ clf_b,
    float* __restrict__ out) {
  __shared__ float ssum[4][64];
  __shared__ float scnt[4];
  int b = blockIdx.x;
  int o = threadIdx.x & 63, sub = threadIdx.x >> 6;
  int base = b * (NN / NBATCH);
  float sum = 0.f, cnt = 0.f;
  for (int j = sub; j < NN / NBATCH; j += 4) {
    int n = base + j;
    if (ct[n] == 1) { sum += h4[n * 64 + o]; cnt += 1.f; }
  }
  ssum[sub][o] = sum;
  if (o == 0) scnt[sub] = cnt;
  __syncthreads();
  if (threadIdx.x < 64) {
    float tot = ssum[0][o] + ssum[1][o] + ssum[2][o] + ssum[3][o];
    float c = scnt[0] + scnt[1] + scnt[2] + scnt[3];
    float v = (tot / fmaxf(c, 1.f)) * clf_w[o];
#pragma unroll
    for (int off = 32; off; off >>= 1) v += __shfl_down(v, off);
    if (o == 0) out[b] = 1.f / (1.f + expf(-(v + clf_b[0])));
  }
}

// ---------------------------------------------------------------------------
extern "C" void kernel_launch(void* const* d_in, const int* in_sizes, int n_in,
                              void* d_out, int out_size, void* d_ws, size_t ws_size,
                              hipStream_t stream) {
  (void)in_sizes; (void)n_in; (void)out_size; (void)ws_size;
  const float* x     = (const float*)d_in[0];
  const int*   eidx  = (const int*)d_in[1];
  const int*   src   = eidx;
  const int*   dst   = eidx + NE;
  const int*   etype = (const int*)d_in[2];
  const float* eattr = (const float*)d_in[3];
  const int*   ct    = (const int*)d_in[4];
  // d_in[5] = batch (structurally arange(N)//1280, unused)
  const float* emb[4], *wh[4], *bh[4], *wg[4], *bg[4], *root[4], *bias[4];
  for (int l = 0; l < 4; l++) {
    int b0 = 6 + 7 * l;
    emb[l]  = (const float*)d_in[b0 + 0];
    wh[l]   = (const float*)d_in[b0 + 1];
    bh[l]   = (const float*)d_in[b0 + 2];
    wg[l]   = (const float*)d_in[b0 + 3];
    bg[l]   = (const float*)d_in[b0 + 4];
    root[l] = (const float*)d_in[b0 + 5];
    bias[l] = (const float*)d_in[b0 + 6];
  }
  const float* clf_w = (const float*)d_in[34];
  const float* clf_b = (const float*)d_in[35];
  float* outp = (float*)d_out;

  float* ws  = (float*)d_ws;
  float* deg = ws;                 // N
  float* h1  = ws + NN;            // 8N
  float* h2  = h1 + 8 * NN;        // 8N
  float* h3  = h2 + 8 * NN;        // 8N
  float* h4  = h3 + 8 * NN;        // 64N
  float* agg = h4 + 64 * NN;       // 64N   (total 153N floats = 12.5 MB)

  // degree (once; graph identical across layers)
  hipMemsetAsync(deg, 0, NN * sizeof(float), stream);
  deg_kernel<<<NE / 256, 256, 0, stream>>>(dst, deg);

  // Layer 1: 16 -> 8
  hipMemsetAsync(agg, 0, NN * 8 * sizeof(float), stream);
  edge_small<16><<<1024, 256, 0, stream>>>(src, dst, etype, eattr, x,
                                           emb[0], wh[0], bh[0], wg[0], bg[0], agg);
  node_kernel<16, 8><<<(NN * 8) / 256, 256, 0, stream>>>(agg, deg, x, root[0], bias[0], h1);

  // Layer 2: 8 -> 8
  hipMemsetAsync(agg, 0, NN * 8 * sizeof(float), stream);
  edge_small<8><<<1024, 256, 0, stream>>>(src, dst, etype, eattr, h1,
                                          emb[1], wh[1], bh[1], wg[1], bg[1], agg);
  node_kernel<8, 8><<<(NN * 8) / 256, 256, 0, stream>>>(agg, deg, h1, root[1], bias[1], h2);

  // Layer 3: 8 -> 8
  hipMemsetAsync(agg, 0, NN * 8 * sizeof(float), stream);
  edge_small<8><<<1024, 256, 0, stream>>>(src, dst, etype, eattr, h2,
                                          emb[2], wh[2], bh[2], wg[2], bg[2], agg);
  node_kernel<8, 8><<<(NN * 8) / 256, 256, 0, stream>>>(agg, deg, h2, root[2], bias[2], h3);

  // Layer 4: 8 -> 64
  hipMemsetAsync(agg, 0, NN * 64 * sizeof(float), stream);
  edge_l4<<<512, 256, 0, stream>>>(src, dst, etype, eattr, h3,
                                   emb[3], wh[3], bh[3], wg[3], bg[3], agg);
  node_kernel<8, 64><<<(NN * 64) / 256, 256, 0, stream>>>(agg, deg, h3, root[3], bias[3], h4);

  // pooling + classifier
  pool_kernel<<<NBATCH, 256, 0, stream>>>(h4, ct, clf_w, clf_b, outp);
}

// Round 2
// 418.668 us; speedup vs baseline: 1.1158x; 1.1158x over previous
//
#include <hip/hip_runtime.h>
#include <math.h>

#define NN 20480
#define NE 327680
#define NBATCH 16

// ---------------- counting-sort: histogram ---------------------------------
__global__ void hist_kernel(const int* __restrict__ dst, int* __restrict__ cnt) {
  int e = blockIdx.x * blockDim.x + threadIdx.x;
  if (e < NE) atomicAdd(&cnt[dst[e]], 1);
}

// ---------------- exclusive scan over NN=20480 counts (1 block, 1024 thr) ---
__global__ __launch_bounds__(1024) void scan_kernel(const int* __restrict__ cnt,
                                                    int* __restrict__ off) {
  __shared__ int part[1024];
  int tid = threadIdx.x;
  const int PT = NN / 1024;              // 20 per thread
  int loc[PT];
  int run = 0;
  int base = tid * PT;
#pragma unroll
  for (int k = 0; k < PT; k++) { loc[k] = run; run += cnt[base + k]; }
  part[tid] = run;
  __syncthreads();
  for (int d = 1; d < 1024; d <<= 1) {
    int t = (tid >= d) ? part[tid - d] : 0;
    __syncthreads();
    part[tid] += t;
    __syncthreads();
  }
  int pre = (tid == 0) ? 0 : part[tid - 1];
#pragma unroll
  for (int k = 0; k < PT; k++) off[base + k] = pre + loc[k];
  if (tid == 1023) off[NN] = pre + run;  // == NE
}

// ---------------- cursor init + scatter into CSR edge records ---------------
__global__ void cursor_kernel(const int* __restrict__ off, int* __restrict__ cur) {
  int i = blockIdx.x * blockDim.x + threadIdx.x;
  if (i < NN) cur[i] = off[i];
}

__global__ void scatter_kernel(const int* __restrict__ src, const int* __restrict__ dst,
                               const int* __restrict__ etype, const float* __restrict__ eattr,
                               int* __restrict__ cur, float4* __restrict__ es) {
  int e = blockIdx.x * blockDim.x + threadIdx.x;
  if (e >= NE) return;
  int d = dst[e];
  int pos = atomicAdd(&cur[d], 1);
  es[pos] = make_float4(__int_as_float(src[e]), __int_as_float(etype[e]),
                        eattr[2 * e], eattr[2 * e + 1]);
}

// ---------------- fused layer, cout==8 (L1..L3) -----------------------------
// One wave per dst node. lane = (e_sub<<3)|o : 8 edges x 8 outputs at a time.
// No atomics: wave owns the node; reduce across e_sub with 3 shfl_xor, then
// mean + root matmul + bias + relu, direct store.
template<int CIN>
__global__ __launch_bounds__(256) void layer_small(
    const int* __restrict__ off, const float4* __restrict__ es,
    const float* __restrict__ h_in,
    const float* __restrict__ emb, const float* __restrict__ wh,
    const float* __restrict__ bh, const float* __restrict__ wg,
    const float* __restrict__ bg,
    const float* __restrict__ root, const float* __restrict__ bias,
    float* __restrict__ h_out) {
  constexpr int D = CIN * 8;
  constexpr int S = D + 1;                 // bank-conflict pad
  __shared__ float semb[36 * S];
  for (int idx = threadIdx.x; idx < 36 * D; idx += 256) {
    int t = idx / D, io = idx - t * D;
    semb[t * S + io] = emb[idx];
  }
  int lane = threadIdx.x & 63;
  int o = lane & 7, esub = lane >> 3;
  float rwh0[CIN], rwh1[CIN], rbh[CIN], rwg0[CIN], rwg1[CIN], rbg[CIN], rroot[CIN];
#pragma unroll
  for (int i = 0; i < CIN; i++) {
    int io = i * 8 + o;
    rwh0[i] = wh[io]; rwh1[i] = wh[D + io]; rbh[i] = bh[io];
    rwg0[i] = wg[io]; rwg1[i] = wg[D + io]; rbg[i] = bg[io];
    rroot[i] = root[io];
  }
  float rbias = bias[o];
  __syncthreads();
  int wid = blockIdx.x * 4 + (threadIdx.x >> 6);
  int TW = gridDim.x * 4;
  for (int n0 = wid; n0 < NN; n0 += TW) {
    int n = __builtin_amdgcn_readfirstlane(n0);   // wave-uniform -> s_loads
    int beg = off[n], end = off[n + 1];
    float acc = 0.f;
    for (int j = beg + esub; j < end; j += 8) {
      float4 rec = es[j];
      int s = __float_as_int(rec.x);
      int t = __float_as_int(rec.y);
      float ef0 = rec.z, ef1 = rec.w;
      const float4* hp = (const float4*)(h_in + s * CIN);
      const float* st = &semb[t * S + o];
      float msg0 = 0.f, msg1 = 0.f;
#pragma unroll
      for (int i4 = 0; i4 < CIN / 4; i4++) {
        float4 hv = hp[i4];
        float hvf[4] = {hv.x, hv.y, hv.z, hv.w};
#pragma unroll
        for (int k = 0; k < 4; k++) {
          int i = i4 * 4 + k;
          float hval = fmaf(ef0, rwh0[i], fmaf(ef1, rwh1[i], rbh[i]));
          float gval = fmaf(ef0, rwg0[i], fmaf(ef1, rwg1[i], rbg[i]));
          float w = fmaxf(fmaf(st[i * 8], hval, gval), 0.f);
          if (k & 1) msg1 = fmaf(hvf[k], w, msg1);
          else       msg0 = fmaf(hvf[k], w, msg0);
        }
      }
      acc += msg0 + msg1;
    }
    acc += __shfl_xor(acc, 8);
    acc += __shfl_xor(acc, 16);
    acc += __shfl_xor(acc, 32);
    float deg = (float)(end - beg);
    float rt = rbias;
    const float* hn = h_in + n * CIN;
#pragma unroll
    for (int i = 0; i < CIN; i++) rt = fmaf(hn[i], rroot[i], rt);
    float val = fmaxf(rt + acc / fmaxf(deg, 1.f), 0.f);
    if (lane < 8) h_out[n * 8 + o] = val;
  }
}

// ---------------- fused layer 4 (cin=8, cout=64) ----------------------------
// One wave per dst node, lane = output channel. Edge record + h row are
// wave-uniform -> scalar loads. emb4 in LDS (b32 reads, 2 lanes/bank = free).
__global__ __launch_bounds__(256) void layer_l4(
    const int* __restrict__ off, const float4* __restrict__ es,
    const float* __restrict__ h_in,
    const float* __restrict__ emb, const float* __restrict__ wh,
    const float* __restrict__ bh, const float* __restrict__ wg,
    const float* __restrict__ bg,
    const float* __restrict__ root, const float* __restrict__ bias,
    float* __restrict__ h_out) {
  __shared__ float semb[36 * 512];
  for (int idx = threadIdx.x; idx < 36 * 512; idx += 256) semb[idx] = emb[idx];
  int lane = threadIdx.x & 63;
  float rwh0[8], rwh1[8], rbh[8], rwg0[8], rwg1[8], rbg[8], rroot[8];
#pragma unroll
  for (int i = 0; i < 8; i++) {
    int io = i * 64 + lane;
    rwh0[i] = wh[io]; rwh1[i] = wh[512 + io]; rbh[i] = bh[io];
    rwg0[i] = wg[io]; rwg1[i] = wg[512 + io]; rbg[i] = bg[io];
    rroot[i] = root[io];
  }
  float rbias = bias[lane];
  __syncthreads();
  int wid = blockIdx.x * 4 + (threadIdx.x >> 6);
  int TW = gridDim.x * 4;
  for (int n0 = wid; n0 < NN; n0 += TW) {
    int n = __builtin_amdgcn_readfirstlane(n0);   // wave-uniform -> s_loads
    int beg = off[n], end = off[n + 1];
    float acc = 0.f;
    for (int e = beg; e < end; ++e) {
      float4 rec = es[e];                         // uniform address
      int s = __float_as_int(rec.x);
      int t = __float_as_int(rec.y);
      float ef0 = rec.z, ef1 = rec.w;
      const float* hp = h_in + s * 8;
      float hv[8];
#pragma unroll
      for (int i = 0; i < 8; i++) hv[i] = hp[i];
      const float* st = &semb[t * 512 + lane];
      float msg0 = 0.f, msg1 = 0.f;
#pragma unroll
      for (int i = 0; i < 8; i++) {
        float hval = fmaf(ef0, rwh0[i], fmaf(ef1, rwh1[i], rbh[i]));
        float gval = fmaf(ef0, rwg0[i], fmaf(ef1, rwg1[i], rbg[i]));
        float w = fmaxf(fmaf(st[i * 64], hval, gval), 0.f);
        if (i & 1) msg1 = fmaf(hv[i], w, msg1);
        else       msg0 = fmaf(hv[i], w, msg0);
      }
      acc += msg0 + msg1;
    }
    float deg = (float)(end - beg);
    float rt = rbias;
    const float* hn = h_in + n * 8;
#pragma unroll
    for (int i = 0; i < 8; i++) rt = fmaf(hn[i], rroot[i], rt);
    h_out[n * 64 + lane] = fmaxf(rt + acc / fmaxf(deg, 1.f), 0.f);
  }
}

// ---------------- gated pooling + classifier + sigmoid ----------------------
__global__ __launch_bounds__(256) void pool_kernel(
    const float* __restrict__ h4, const int* __restrict__ ct,
    const float* __restrict__ clf_w, const float* __restrict__ clf_b,
    float* __restrict__ out) {
  __shared__ float ssum[4][64];
  __shared__ float scnt[4];
  int b = blockIdx.x;
  int o = threadIdx.x & 63, sub = threadIdx.x >> 6;
  int base = b * (NN / NBATCH);
  float sum = 0.f, cnt = 0.f;
  for (int j = sub; j < NN / NBATCH; j += 4) {
    int n = base + j;
    if (ct[n] == 1) { sum += h4[n * 64 + o]; cnt += 1.f; }
  }
  ssum[sub][o] = sum;
  if (o == 0) scnt[sub] = cnt;
  __syncthreads();
  if (threadIdx.x < 64) {
    float tot = ssum[0][o] + ssum[1][o] + ssum[2][o] + ssum[3][o];
    float c = scnt[0] + scnt[1] + scnt[2] + scnt[3];
    float v = (tot / fmaxf(c, 1.f)) * clf_w[o];
#pragma unroll
    for (int off = 32; off; off >>= 1) v += __shfl_down(v, off);
    if (o == 0) out[b] = 1.f / (1.f + expf(-(v + clf_b[0])));
  }
}

// ---------------------------------------------------------------------------
extern "C" void kernel_launch(void* const* d_in, const int* in_sizes, int n_in,
                              void* d_out, int out_size, void* d_ws, size_t ws_size,
                              hipStream_t stream) {
  (void)in_sizes; (void)n_in; (void)out_size; (void)ws_size;
  const float* x     = (const float*)d_in[0];
  const int*   eidx  = (const int*)d_in[1];
  const int*   src   = eidx;
  const int*   dst   = eidx + NE;
  const int*   etype = (const int*)d_in[2];
  const float* eattr = (const float*)d_in[3];
  const int*   ct    = (const int*)d_in[4];
  const float *emb[4], *wh[4], *bh[4], *wg[4], *bg[4], *root[4], *bias[4];
  for (int l = 0; l < 4; l++) {
    int b0 = 6 + 7 * l;
    emb[l]  = (const float*)d_in[b0 + 0];
    wh[l]   = (const float*)d_in[b0 + 1];
    bh[l]   = (const float*)d_in[b0 + 2];
    wg[l]   = (const float*)d_in[b0 + 3];
    bg[l]   = (const float*)d_in[b0 + 4];
    root[l] = (const float*)d_in[b0 + 5];
    bias[l] = (const float*)d_in[b0 + 6];
  }
  const float* clf_w = (const float*)d_in[34];
  const float* clf_b = (const float*)d_in[35];
  float* outp = (float*)d_out;

  // workspace layout (floats); total = 2,969,604 floats = 11.88 MB (< 12.53 MB
  // proven available by round 1). cnt/cursor alias the h4 region (dead until L4).
  float* ws  = (float*)d_ws;
  int*    off  = (int*)ws;                        // NN+1 (padded to 20484)
  float4* es   = (float4*)(ws + 20484);           // NE float4
  float*  hA   = ws + 20484 + 4 * NE;             // 8N
  float*  hB   = hA + 8 * NN;                     // 8N
  float*  h4   = hB + 8 * NN;                     // 64N
  int*    cnt  = (int*)h4;                        // NN  (alias, dead before L4)
  int*    cur  = cnt + NN;                        // NN  (alias)

  // ---- build CSR by dst (graph identical across all 4 layers) ----
  hipMemsetAsync(cnt, 0, NN * sizeof(int), stream);
  hist_kernel<<<NE / 256, 256, 0, stream>>>(dst, cnt);
  scan_kernel<<<1, 1024, 0, stream>>>(cnt, off);
  cursor_kernel<<<(NN + 255) / 256, 256, 0, stream>>>(off, cur);
  scatter_kernel<<<NE / 256, 256, 0, stream>>>(src, dst, etype, eattr, cur, es);

  // ---- 4 fused layers (edge NN + message + mean + root + bias + relu) ----
  layer_small<16><<<1024, 256, 0, stream>>>(off, es, x,
      emb[0], wh[0], bh[0], wg[0], bg[0], root[0], bias[0], hA);
  layer_small<8><<<1024, 256, 0, stream>>>(off, es, hA,
      emb[1], wh[1], bh[1], wg[1], bg[1], root[1], bias[1], hB);
  layer_small<8><<<1024, 256, 0, stream>>>(off, es, hB,
      emb[2], wh[2], bh[2], wg[2], bg[2], root[2], bias[2], hA);
  layer_l4<<<512, 256, 0, stream>>>(off, es, hA,
      emb[3], wh[3], bh[3], wg[3], bg[3], root[3], bias[3], h4);

  // ---- pooling + classifier + sigmoid ----
  pool_kernel<<<NBATCH, 256, 0, stream>>>(h4, ct, clf_w, clf_b, outp);
}

// Round 3
// 328.834 us; speedup vs baseline: 1.4206x; 1.2732x over previous
//
#include <hip/hip_runtime.h>
#include <math.h>

#define NN 20480
#define NE 327680
#define NBATCH 16

typedef float v2f __attribute__((ext_vector_type(2)));

#if __has_builtin(__builtin_elementwise_max)
#define VMAX0(a) __builtin_elementwise_max((a), (v2f){0.f, 0.f})
#else
static __device__ __forceinline__ v2f VMAX0(v2f a) {
  v2f r; r.x = fmaxf(a.x, 0.f); r.y = fmaxf(a.y, 0.f); return r;
}
#endif

// ---------------- counting-sort: histogram ---------------------------------
__global__ void hist_kernel(const int* __restrict__ dst, int* __restrict__ cnt) {
  int e = blockIdx.x * blockDim.x + threadIdx.x;
  if (e < NE) atomicAdd(&cnt[dst[e]], 1);
}

// ---------------- exclusive scan over NN counts (1 block, 1024 thr) ---------
__global__ __launch_bounds__(1024) void scan_kernel(const int* __restrict__ cnt,
                                                    int* __restrict__ off) {
  __shared__ int part[1024];
  int tid = threadIdx.x;
  const int PT = NN / 1024;              // 20 per thread
  int loc[PT];
  int run = 0;
  int base = tid * PT;
#pragma unroll
  for (int k = 0; k < PT; k++) { loc[k] = run; run += cnt[base + k]; }
  part[tid] = run;
  __syncthreads();
  for (int d = 1; d < 1024; d <<= 1) {
    int t = (tid >= d) ? part[tid - d] : 0;
    __syncthreads();
    part[tid] += t;
    __syncthreads();
  }
  int pre = (tid == 0) ? 0 : part[tid - 1];
#pragma unroll
  for (int k = 0; k < PT; k++) off[base + k] = pre + loc[k];
  if (tid == 1023) off[NN] = pre + run;  // == NE
}

__global__ void cursor_kernel(const int* __restrict__ off, int* __restrict__ cur) {
  int i = blockIdx.x * blockDim.x + threadIdx.x;
  if (i < NN) cur[i] = off[i];
}

__global__ void scatter_kernel(const int* __restrict__ src, const int* __restrict__ dst,
                               const int* __restrict__ etype, const float* __restrict__ eattr,
                               int* __restrict__ cur, float4* __restrict__ es) {
  int e = blockIdx.x * blockDim.x + threadIdx.x;
  if (e >= NE) return;
  int d = dst[e];
  int pos = atomicAdd(&cur[d], 1);
  es[pos] = make_float4(__int_as_float(src[e]), __int_as_float(etype[e]),
                        eattr[2 * e], eattr[2 * e + 1]);
}

// ---------------- fused layer, cout==8 (L1..L3) -----------------------------
// 1280 blocks x 4 waves, 4 nodes per wave. lane=(e_sub<<3)|o: 8 edges x 8 out.
// Inner i-loop in float2 pairs -> v_pk_fma_f32 / ds_read2_b32.
template<int CIN>
__global__ __launch_bounds__(256) void layer_small(
    const int* __restrict__ off, const float4* __restrict__ es,
    const float* __restrict__ h_in,
    const float* __restrict__ emb, const float* __restrict__ wh,
    const float* __restrict__ bh, const float* __restrict__ wg,
    const float* __restrict__ bg,
    const float* __restrict__ root, const float* __restrict__ bias,
    float* __restrict__ h_out) {
  constexpr int D = CIN * 8;
  constexpr int S = D + 1;                 // odd stride: spreads banks by etype
  constexpr int P = CIN / 2;
  __shared__ float semb[36 * S];
  for (int idx = threadIdx.x; idx < 36 * D; idx += 256) {
    int t = idx / D, io = idx - t * D;
    semb[t * S + io] = emb[idx];
  }
  int lane = threadIdx.x & 63;
  int o = lane & 7, esub = lane >> 3;
  v2f rwh0[P], rwh1[P], rbh[P], rwg0[P], rwg1[P], rbg[P], rroot[P];
#pragma unroll
  for (int p = 0; p < P; p++) {
    int a = (2 * p) * 8 + o, b = (2 * p + 1) * 8 + o;
    rwh0[p] = (v2f){wh[a], wh[b]};
    rwh1[p] = (v2f){wh[D + a], wh[D + b]};
    rbh[p]  = (v2f){bh[a], bh[b]};
    rwg0[p] = (v2f){wg[a], wg[b]};
    rwg1[p] = (v2f){wg[D + a], wg[D + b]};
    rbg[p]  = (v2f){bg[a], bg[b]};
    rroot[p] = (v2f){root[a], root[b]};
  }
  float rbias = bias[o];
  __syncthreads();
  int wid = __builtin_amdgcn_readfirstlane(blockIdx.x * 4 + (threadIdx.x >> 6));
  for (int k = 0; k < 4; k++) {
    int n = wid * 4 + k;
    int beg = off[n], end = off[n + 1];
    float acc = 0.f;
    for (int j = beg + esub; j < end; j += 8) {
      float4 rec = es[j];
      int s = __float_as_int(rec.x);
      int t = __float_as_int(rec.y);
      v2f ef0 = (v2f){rec.z, rec.z}, ef1 = (v2f){rec.w, rec.w};
      const float4* hp = (const float4*)(h_in + s * CIN);
      const float* st = &semb[t * S + o];
      v2f msg = {0.f, 0.f};
#pragma unroll
      for (int q = 0; q < CIN / 4; q++) {
        float4 hv4 = hp[q];
        v2f hv0 = (v2f){hv4.x, hv4.y}, hv1 = (v2f){hv4.z, hv4.w};
        int p0 = 2 * q, p1 = 2 * q + 1;
        v2f hA = ef0 * rwh0[p0] + ef1 * rwh1[p0] + rbh[p0];
        v2f gA = ef0 * rwg0[p0] + ef1 * rwg1[p0] + rbg[p0];
        v2f sA = (v2f){st[(4 * q) * 8], st[(4 * q + 1) * 8]};
        msg += hv0 * VMAX0(sA * hA + gA);
        v2f hB = ef0 * rwh0[p1] + ef1 * rwh1[p1] + rbh[p1];
        v2f gB = ef0 * rwg0[p1] + ef1 * rwg1[p1] + rbg[p1];
        v2f sB = (v2f){st[(4 * q + 2) * 8], st[(4 * q + 3) * 8]};
        msg += hv1 * VMAX0(sB * hB + gB);
      }
      acc += msg.x + msg.y;
    }
    acc += __shfl_xor(acc, 8);
    acc += __shfl_xor(acc, 16);
    acc += __shfl_xor(acc, 32);
    float deg = (float)(end - beg);
    const float* hn = h_in + n * CIN;
    v2f rtv = {rbias, 0.f};
#pragma unroll
    for (int p = 0; p < P; p++)
      rtv += (v2f){hn[2 * p], hn[2 * p + 1]} * rroot[p];
    float val = fmaxf(rtv.x + rtv.y + acc / fmaxf(deg, 1.f), 0.f);
    if (lane < 8) h_out[n * 8 + o] = val;
  }
}

// ---------------- fused layer 4 (cin=8, cout=64) ----------------------------
// 640 blocks x 8 waves, 4 nodes per wave, lane = output channel.
// Edge record + h row wave-uniform -> s_loads. i-loop in float2 pairs.
__global__ __launch_bounds__(512) void layer_l4(
    const int* __restrict__ off, const float4* __restrict__ es,
    const float* __restrict__ h_in,
    const float* __restrict__ emb, const float* __restrict__ wh,
    const float* __restrict__ bh, const float* __restrict__ wg,
    const float* __restrict__ bg,
    const float* __restrict__ root, const float* __restrict__ bias,
    float* __restrict__ h_out) {
  __shared__ float semb[36 * 512];
  {
    const float4* e4 = (const float4*)emb;
    float4* s4 = (float4*)semb;
    for (int idx = threadIdx.x; idx < 36 * 128; idx += 512) s4[idx] = e4[idx];
  }
  int lane = threadIdx.x & 63;
  v2f rwh0[4], rwh1[4], rbh[4], rwg0[4], rwg1[4], rbg[4], rroot[4];
#pragma unroll
  for (int p = 0; p < 4; p++) {
    int a = (2 * p) * 64 + lane, b = (2 * p + 1) * 64 + lane;
    rwh0[p] = (v2f){wh[a], wh[b]};
    rwh1[p] = (v2f){wh[512 + a], wh[512 + b]};
    rbh[p]  = (v2f){bh[a], bh[b]};
    rwg0[p] = (v2f){wg[a], wg[b]};
    rwg1[p] = (v2f){wg[512 + a], wg[512 + b]};
    rbg[p]  = (v2f){bg[a], bg[b]};
    rroot[p] = (v2f){root[a], root[b]};
  }
  float rbias = bias[lane];
  __syncthreads();
  int wid = __builtin_amdgcn_readfirstlane(blockIdx.x * 8 + (threadIdx.x >> 6));
  for (int k = 0; k < 4; k++) {
    int n = wid * 4 + k;
    int beg = off[n], end = off[n + 1];
    float acc = 0.f;
    for (int e = beg; e < end; ++e) {
      float4 rec = es[e];                         // uniform -> s_load
      int s = __float_as_int(rec.x);
      int t = __float_as_int(rec.y);
      v2f ef0 = (v2f){rec.z, rec.z}, ef1 = (v2f){rec.w, rec.w};
      const float4* hp = (const float4*)(h_in + s * 8);
      float4 h0 = hp[0], h1 = hp[1];
      v2f hv[4] = {(v2f){h0.x, h0.y}, (v2f){h0.z, h0.w},
                   (v2f){h1.x, h1.y}, (v2f){h1.z, h1.w}};
      const float* st = &semb[t * 512 + lane];
      v2f msg = {0.f, 0.f};
#pragma unroll
      for (int p = 0; p < 4; p++) {
        v2f hval = ef0 * rwh0[p] + ef1 * rwh1[p] + rbh[p];
        v2f gval = ef0 * rwg0[p] + ef1 * rwg1[p] + rbg[p];
        v2f stv = (v2f){st[(2 * p) * 64], st[(2 * p + 1) * 64]};
        msg += hv[p] * VMAX0(stv * hval + gval);
      }
      acc += msg.x + msg.y;
    }
    float deg = (float)(end - beg);
    const float* hn = h_in + n * 8;
    v2f rtv = {rbias, 0.f};
#pragma unroll
    for (int p = 0; p < 4; p++)
      rtv += (v2f){hn[2 * p], hn[2 * p + 1]} * rroot[p];
    h_out[n * 64 + lane] = fmaxf(rtv.x + rtv.y + acc / fmaxf(deg, 1.f), 0.f);
  }
}

// ---------------- gated pooling, phase 1: 320 blocks ------------------------
__global__ __launch_bounds__(256) void pool1_kernel(
    const float* __restrict__ h4, const int* __restrict__ ct,
    float* __restrict__ pooled, float* __restrict__ pcnt) {
  __shared__ float ss[4][64];
  __shared__ float sc[4];
  int b = blockIdx.x / 20, c = blockIdx.x % 20;
  int base = b * (NN / NBATCH) + c * 64;
  int o = threadIdx.x & 63, sub = threadIdx.x >> 6;
  float sum = 0.f, cnt = 0.f;
  for (int j = sub; j < 64; j += 4) {
    int n = base + j;
    if (ct[n] == 1) { sum += h4[n * 64 + o]; cnt += 1.f; }
  }
  ss[sub][o] = sum;
  if (o == 0) sc[sub] = cnt;
  __syncthreads();
  if (threadIdx.x < 64) {
    float tot = ss[0][o] + ss[1][o] + ss[2][o] + ss[3][o];
    unsafeAtomicAdd(&pooled[b * 64 + o], tot);
    if (o == 0) unsafeAtomicAdd(&pcnt[b], sc[0] + sc[1] + sc[2] + sc[3]);
  }
}

// ---------------- pooling phase 2 + classifier + sigmoid (1 block) ----------
__global__ __launch_bounds__(1024) void pool2_kernel(
    const float* __restrict__ pooled, const float* __restrict__ pcnt,
    const float* __restrict__ clf_w, const float* __restrict__ clf_b,
    float* __restrict__ out) {
  int b = threadIdx.x >> 6, o = threadIdx.x & 63;
  float c = pcnt[b];
  float v = (pooled[b * 64 + o] / fmaxf(c, 1.f)) * clf_w[o];
#pragma unroll
  for (int d = 32; d; d >>= 1) v += __shfl_down(v, d);
  if (o == 0) out[b] = 1.f / (1.f + expf(-(v + clf_b[0])));
}

// ---------------------------------------------------------------------------
extern "C" void kernel_launch(void* const* d_in, const int* in_sizes, int n_in,
                              void* d_out, int out_size, void* d_ws, size_t ws_size,
                              hipStream_t stream) {
  (void)in_sizes; (void)n_in; (void)out_size; (void)ws_size;
  const float* x     = (const float*)d_in[0];
  const int*   eidx  = (const int*)d_in[1];
  const int*   src   = eidx;
  const int*   dst   = eidx + NE;
  const int*   etype = (const int*)d_in[2];
  const float* eattr = (const float*)d_in[3];
  const int*   ct    = (const int*)d_in[4];
  const float *emb[4], *wh[4], *bh[4], *wg[4], *bg[4], *root[4], *bias[4];
  for (int l = 0; l < 4; l++) {
    int b0 = 6 + 7 * l;
    emb[l]  = (const float*)d_in[b0 + 0];
    wh[l]   = (const float*)d_in[b0 + 1];
    bh[l]   = (const float*)d_in[b0 + 2];
    wg[l]   = (const float*)d_in[b0 + 3];
    bg[l]   = (const float*)d_in[b0 + 4];
    root[l] = (const float*)d_in[b0 + 5];
    bias[l] = (const float*)d_in[b0 + 6];
  }
  const float* clf_w = (const float*)d_in[34];
  const float* clf_b = (const float*)d_in[35];
  float* outp = (float*)d_out;

  // workspace layout (floats), ~11.9 MB (ws proven >= 12.5 MB in round 1)
  float* ws  = (float*)d_ws;
  int*    off    = (int*)ws;                      // NN+1 (pad 20484)
  float4* es     = (float4*)(ws + 20484);         // NE float4
  float*  hA     = ws + 20484 + 4 * NE;           // 8N
  float*  hB     = hA + 8 * NN;                   // 8N
  float*  h4     = hB + 8 * NN;                   // 64N
  float*  pooled = h4 + 64 * NN;                  // 16*64
  float*  pcnt   = pooled + 16 * 64;              // 16
  int*    cnt    = (int*)h4;                      // alias (dead until L4)
  int*    cur    = cnt + NN;                      // alias

  // ---- build CSR by dst (graph identical across all 4 layers) ----
  hipMemsetAsync(cnt, 0, NN * sizeof(int), stream);
  hipMemsetAsync(pooled, 0, (16 * 64 + 16) * sizeof(float), stream);
  hist_kernel<<<NE / 256, 256, 0, stream>>>(dst, cnt);
  scan_kernel<<<1, 1024, 0, stream>>>(cnt, off);
  cursor_kernel<<<(NN + 255) / 256, 256, 0, stream>>>(off, cur);
  scatter_kernel<<<NE / 256, 256, 0, stream>>>(src, dst, etype, eattr, cur, es);

  // ---- 4 fused layers ----
  layer_small<16><<<1280, 256, 0, stream>>>(off, es, x,
      emb[0], wh[0], bh[0], wg[0], bg[0], root[0], bias[0], hA);
  layer_small<8><<<1280, 256, 0, stream>>>(off, es, hA,
      emb[1], wh[1], bh[1], wg[1], bg[1], root[1], bias[1], hB);
  layer_small<8><<<1280, 256, 0, stream>>>(off, es, hB,
      emb[2], wh[2], bh[2], wg[2], bg[2], root[2], bias[2], hA);
  layer_l4<<<640, 512, 0, stream>>>(off, es, hA,
      emb[3], wh[3], bh[3], wg[3], bg[3], root[3], bias[3], h4);

  // ---- pooling + classifier + sigmoid ----
  pool1_kernel<<<320, 256, 0, stream>>>(h4, ct, pooled, pcnt);
  pool2_kernel<<<1, 1024, 0, stream>>>(pooled, pcnt, clf_w, clf_b, outp);
}

// Round 4
// 298.648 us; speedup vs baseline: 1.5642x; 1.1011x over previous
//
#include <hip/hip_runtime.h>
#include <math.h>

#define NN 20480
#define NE 327680
#define NBATCH 16

typedef float v2f __attribute__((ext_vector_type(2)));

#if __has_builtin(__builtin_elementwise_max)
#define VMAX0(a) __builtin_elementwise_max((a), (v2f){0.f, 0.f})
#else
static __device__ __forceinline__ v2f VMAX0(v2f a) {
  v2f r; r.x = fmaxf(a.x, 0.f); r.y = fmaxf(a.y, 0.f); return r;
}
#endif

// ---------------- counting-sort: histogram ---------------------------------
__global__ void hist_kernel(const int* __restrict__ dst, int* __restrict__ cnt) {
  int e = blockIdx.x * blockDim.x + threadIdx.x;
  if (e < NE) atomicAdd(&cnt[dst[e]], 1);
}

// ------- exclusive scan over NN counts (1 block); writes off AND cur --------
__global__ __launch_bounds__(1024) void scan_kernel(const int* __restrict__ cnt,
                                                    int* __restrict__ off,
                                                    int* __restrict__ cur) {
  __shared__ int part[1024];
  int tid = threadIdx.x;
  const int PT = NN / 1024;              // 20 per thread
  int loc[PT];
  int run = 0;
  int base = tid * PT;
#pragma unroll
  for (int k = 0; k < PT; k++) { loc[k] = run; run += cnt[base + k]; }
  part[tid] = run;
  __syncthreads();
  for (int d = 1; d < 1024; d <<= 1) {
    int t = (tid >= d) ? part[tid - d] : 0;
    __syncthreads();
    part[tid] += t;
    __syncthreads();
  }
  int pre = (tid == 0) ? 0 : part[tid - 1];
#pragma unroll
  for (int k = 0; k < PT; k++) {
    off[base + k] = pre + loc[k];
    cur[base + k] = pre + loc[k];
  }
  if (tid == 1023) off[NN] = pre + run;  // == NE
}

__global__ void scatter_kernel(const int* __restrict__ src, const int* __restrict__ dst,
                               const int* __restrict__ etype, const float* __restrict__ eattr,
                               int* __restrict__ cur, float4* __restrict__ es) {
  int e = blockIdx.x * blockDim.x + threadIdx.x;
  if (e >= NE) return;
  int d = dst[e];
  int pos = atomicAdd(&cur[d], 1);
  es[pos] = make_float4(__int_as_float(src[e]), __int_as_float(etype[e]),
                        eattr[2 * e], eattr[2 * e + 1]);
}

// ---------------- fused layer 1 (cin=16, cout=8) ----------------------------
// lane = (edge[2b] << 4) | (ihalf << 3) | o : 4 edges x 2 input-halves x 8 out.
// Each lane holds params for only 8 of the 16 inputs -> 56 VGPR of params
// (vs 112 with full-i mapping) -> ~5 waves/SIMD. 2 nodes per wave.
__global__ __launch_bounds__(256) void layer_small16(
    const int* __restrict__ off, const float4* __restrict__ es,
    const float* __restrict__ h_in,
    const float* __restrict__ emb, const float* __restrict__ wh,
    const float* __restrict__ bh, const float* __restrict__ wg,
    const float* __restrict__ bg,
    const float* __restrict__ root, const float* __restrict__ bias,
    float* __restrict__ h_out) {
  constexpr int D = 128;
  constexpr int S = D + 1;               // odd stride spreads banks
  __shared__ float semb[36 * S];
  for (int idx = threadIdx.x; idx < 36 * D; idx += 256) {
    int t = idx / D, io = idx - t * D;
    semb[t * S + io] = emb[idx];
  }
  int lane = threadIdx.x & 63;
  int o = lane & 7;
  int ihalf = (lane >> 3) & 1;
  int esub = lane >> 4;                  // 0..3
  int ibase = ihalf * 8;
  v2f rwh0[4], rwh1[4], rbh[4], rwg0[4], rwg1[4], rbg[4], rroot[4];
#pragma unroll
  for (int p = 0; p < 4; p++) {
    int a = (ibase + 2 * p) * 8 + o, b = (ibase + 2 * p + 1) * 8 + o;
    rwh0[p] = (v2f){wh[a], wh[b]};
    rwh1[p] = (v2f){wh[D + a], wh[D + b]};
    rbh[p]  = (v2f){bh[a], bh[b]};
    rwg0[p] = (v2f){wg[a], wg[b]};
    rwg1[p] = (v2f){wg[D + a], wg[D + b]};
    rbg[p]  = (v2f){bg[a], bg[b]};
    rroot[p] = (v2f){root[a], root[b]};
  }
  float rbias = bias[o];
  __syncthreads();
  int wid = __builtin_amdgcn_readfirstlane(blockIdx.x * 4 + (threadIdx.x >> 6));
  for (int k = 0; k < 2; k++) {
    int n = wid * 2 + k;
    int beg = off[n], end = off[n + 1];
    float acc = 0.f;
    for (int j = beg + esub; j < end; j += 4) {
      float4 rec = es[j];
      int s = __float_as_int(rec.x);
      int t = __float_as_int(rec.y);
      v2f ef0 = (v2f){rec.z, rec.z}, ef1 = (v2f){rec.w, rec.w};
      const float4* hp = (const float4*)(h_in + s * 16 + ibase);
      float4 h0 = hp[0], h1 = hp[1];
      v2f hv[4] = {(v2f){h0.x, h0.y}, (v2f){h0.z, h0.w},
                   (v2f){h1.x, h1.y}, (v2f){h1.z, h1.w}};
      const float* st = &semb[t * S + ibase * 8 + o];
      v2f msg = {0.f, 0.f};
#pragma unroll
      for (int p = 0; p < 4; p++) {
        v2f hval = ef0 * rwh0[p] + ef1 * rwh1[p] + rbh[p];
        v2f gval = ef0 * rwg0[p] + ef1 * rwg1[p] + rbg[p];
        v2f stv = (v2f){st[(2 * p) * 8], st[(2 * p + 1) * 8]};
        msg += hv[p] * VMAX0(stv * hval + gval);
      }
      acc += msg.x + msg.y;
    }
    // msg reduce: xor8 combines i-halves (same edge), xor16/32 combine edges
    acc += __shfl_xor(acc, 8);
    acc += __shfl_xor(acc, 16);
    acc += __shfl_xor(acc, 32);
    // root partial over this lane's i-half; xor8 completes it (dupes across esub)
    const float* hn = h_in + n * 16 + ibase;
    v2f rtv = {0.f, 0.f};
#pragma unroll
    for (int p = 0; p < 4; p++)
      rtv += (v2f){hn[2 * p], hn[2 * p + 1]} * rroot[p];
    float rt = rtv.x + rtv.y;
    rt += __shfl_xor(rt, 8);
    float deg = (float)(end - beg);
    float val = fmaxf(rbias + rt + acc / fmaxf(deg, 1.f), 0.f);
    if (lane < 8) h_out[n * 8 + o] = val;
  }
}

// ---------------- fused layer, cin=8 cout=8 (L2,L3) -------------------------
// lane = (e_sub<<3)|o: 8 edges x 8 outputs. 4 nodes per wave.
__global__ __launch_bounds__(256) void layer_small8(
    const int* __restrict__ off, const float4* __restrict__ es,
    const float* __restrict__ h_in,
    const float* __restrict__ emb, const float* __restrict__ wh,
    const float* __restrict__ bh, const float* __restrict__ wg,
    const float* __restrict__ bg,
    const float* __restrict__ root, const float* __restrict__ bias,
    float* __restrict__ h_out) {
  constexpr int D = 64;
  constexpr int S = D + 1;
  __shared__ float semb[36 * S];
  for (int idx = threadIdx.x; idx < 36 * D; idx += 256) {
    int t = idx / D, io = idx - t * D;
    semb[t * S + io] = emb[idx];
  }
  int lane = threadIdx.x & 63;
  int o = lane & 7, esub = lane >> 3;
  v2f rwh0[4], rwh1[4], rbh[4], rwg0[4], rwg1[4], rbg[4], rroot[4];
#pragma unroll
  for (int p = 0; p < 4; p++) {
    int a = (2 * p) * 8 + o, b = (2 * p + 1) * 8 + o;
    rwh0[p] = (v2f){wh[a], wh[b]};
    rwh1[p] = (v2f){wh[D + a], wh[D + b]};
    rbh[p]  = (v2f){bh[a], bh[b]};
    rwg0[p] = (v2f){wg[a], wg[b]};
    rwg1[p] = (v2f){wg[D + a], wg[D + b]};
    rbg[p]  = (v2f){bg[a], bg[b]};
    rroot[p] = (v2f){root[a], root[b]};
  }
  float rbias = bias[o];
  __syncthreads();
  int wid = __builtin_amdgcn_readfirstlane(blockIdx.x * 4 + (threadIdx.x >> 6));
  for (int k = 0; k < 4; k++) {
    int n = wid * 4 + k;
    int beg = off[n], end = off[n + 1];
    float acc = 0.f;
    for (int j = beg + esub; j < end; j += 8) {
      float4 rec = es[j];
      int s = __float_as_int(rec.x);
      int t = __float_as_int(rec.y);
      v2f ef0 = (v2f){rec.z, rec.z}, ef1 = (v2f){rec.w, rec.w};
      const float4* hp = (const float4*)(h_in + s * 8);
      float4 h0 = hp[0], h1 = hp[1];
      v2f hv[4] = {(v2f){h0.x, h0.y}, (v2f){h0.z, h0.w},
                   (v2f){h1.x, h1.y}, (v2f){h1.z, h1.w}};
      const float* st = &semb[t * S + o];
      v2f msg = {0.f, 0.f};
#pragma unroll
      for (int p = 0; p < 4; p++) {
        v2f hval = ef0 * rwh0[p] + ef1 * rwh1[p] + rbh[p];
        v2f gval = ef0 * rwg0[p] + ef1 * rwg1[p] + rbg[p];
        v2f stv = (v2f){st[(2 * p) * 8], st[(2 * p + 1) * 8]};
        msg += hv[p] * VMAX0(stv * hval + gval);
      }
      acc += msg.x + msg.y;
    }
    acc += __shfl_xor(acc, 8);
    acc += __shfl_xor(acc, 16);
    acc += __shfl_xor(acc, 32);
    float deg = (float)(end - beg);
    const float* hn = h_in + n * 8;
    v2f rtv = {0.f, 0.f};
#pragma unroll
    for (int p = 0; p < 4; p++)
      rtv += (v2f){hn[2 * p], hn[2 * p + 1]} * rroot[p];
    float val = fmaxf(rbias + rtv.x + rtv.y + acc / fmaxf(deg, 1.f), 0.f);
    if (lane < 8) h_out[n * 8 + o] = val;
  }
}

// ---------------- fused layer 4 (cin=8, cout=64) ----------------------------
// NO LDS: emb4 (72KB) is served from L1/L2, coalesced 256B wave-loads.
// One node per wave (20480 waves), edge loop unrolled x2 with independent
// accumulators -> many independent latency chains per SIMD.
__global__ __launch_bounds__(256) void layer_l4(
    const int* __restrict__ off, const float4* __restrict__ es,
    const float* __restrict__ h_in,
    const float* __restrict__ emb, const float* __restrict__ wh,
    const float* __restrict__ bh, const float* __restrict__ wg,
    const float* __restrict__ bg,
    const float* __restrict__ root, const float* __restrict__ bias,
    float* __restrict__ h_out) {
  int lane = threadIdx.x & 63;
  v2f rwh0[4], rwh1[4], rbh[4], rwg0[4], rwg1[4], rbg[4], rroot[4];
#pragma unroll
  for (int p = 0; p < 4; p++) {
    int a = (2 * p) * 64 + lane, b = (2 * p + 1) * 64 + lane;
    rwh0[p] = (v2f){wh[a], wh[b]};
    rwh1[p] = (v2f){wh[512 + a], wh[512 + b]};
    rbh[p]  = (v2f){bh[a], bh[b]};
    rwg0[p] = (v2f){wg[a], wg[b]};
    rwg1[p] = (v2f){wg[512 + a], wg[512 + b]};
    rbg[p]  = (v2f){bg[a], bg[b]};
    rroot[p] = (v2f){root[a], root[b]};
  }
  float rbias = bias[lane];
  int n = __builtin_amdgcn_readfirstlane(blockIdx.x * 4 + (threadIdx.x >> 6));
  int beg = off[n], end = off[n + 1];
  float acc0 = 0.f, acc1 = 0.f;
  int e = beg;
  for (; e + 2 <= end; e += 2) {
    float4 r0 = es[e], r1 = es[e + 1];            // uniform -> s_loads
    int s0 = __float_as_int(r0.x), t0 = __float_as_int(r0.y);
    int s1 = __float_as_int(r1.x), t1 = __float_as_int(r1.y);
    const float4* hp0 = (const float4*)(h_in + s0 * 8);
    const float4* hp1 = (const float4*)(h_in + s1 * 8);
    float4 a0 = hp0[0], a1 = hp0[1];
    float4 b0 = hp1[0], b1 = hp1[1];
    const float* st0 = emb + t0 * 512 + lane;
    const float* st1 = emb + t1 * 512 + lane;
    v2f sv0[4], sv1[4];
#pragma unroll
    for (int p = 0; p < 4; p++) sv0[p] = (v2f){st0[(2 * p) * 64], st0[(2 * p + 1) * 64]};
#pragma unroll
    for (int p = 0; p < 4; p++) sv1[p] = (v2f){st1[(2 * p) * 64], st1[(2 * p + 1) * 64]};
    v2f hva[4] = {(v2f){a0.x, a0.y}, (v2f){a0.z, a0.w},
                  (v2f){a1.x, a1.y}, (v2f){a1.z, a1.w}};
    v2f hvb[4] = {(v2f){b0.x, b0.y}, (v2f){b0.z, b0.w},
                  (v2f){b1.x, b1.y}, (v2f){b1.z, b1.w}};
    v2f e00 = (v2f){r0.z, r0.z}, e01 = (v2f){r0.w, r0.w};
    v2f e10 = (v2f){r1.z, r1.z}, e11 = (v2f){r1.w, r1.w};
    v2f m0 = {0.f, 0.f}, m1 = {0.f, 0.f};
#pragma unroll
    for (int p = 0; p < 4; p++) {
      v2f hv0 = e00 * rwh0[p] + e01 * rwh1[p] + rbh[p];
      v2f gv0 = e00 * rwg0[p] + e01 * rwg1[p] + rbg[p];
      m0 += hva[p] * VMAX0(sv0[p] * hv0 + gv0);
      v2f hv1 = e10 * rwh0[p] + e11 * rwh1[p] + rbh[p];
      v2f gv1 = e10 * rwg0[p] + e11 * rwg1[p] + rbg[p];
      m1 += hvb[p] * VMAX0(sv1[p] * hv1 + gv1);
    }
    acc0 += m0.x + m0.y;
    acc1 += m1.x + m1.y;
  }
  if (e < end) {
    float4 r0 = es[e];
    int s0 = __float_as_int(r0.x), t0 = __float_as_int(r0.y);
    const float4* hp0 = (const float4*)(h_in + s0 * 8);
    float4 a0 = hp0[0], a1 = hp0[1];
    const float* st0 = emb + t0 * 512 + lane;
    v2f hva[4] = {(v2f){a0.x, a0.y}, (v2f){a0.z, a0.w},
                  (v2f){a1.x, a1.y}, (v2f){a1.z, a1.w}};
    v2f e00 = (v2f){r0.z, r0.z}, e01 = (v2f){r0.w, r0.w};
    v2f m0 = {0.f, 0.f};
#pragma unroll
    for (int p = 0; p < 4; p++) {
      v2f hv0 = e00 * rwh0[p] + e01 * rwh1[p] + rbh[p];
      v2f gv0 = e00 * rwg0[p] + e01 * rwg1[p] + rbg[p];
      v2f stv = (v2f){st0[(2 * p) * 64], st0[(2 * p + 1) * 64]};
      m0 += hva[p] * VMAX0(stv * hv0 + gv0);
    }
    acc0 += m0.x + m0.y;
  }
  float acc = acc0 + acc1;
  float deg = (float)(end - beg);
  const float* hn = h_in + n * 8;
  v2f rtv = {0.f, 0.f};
#pragma unroll
  for (int p = 0; p < 4; p++)
    rtv += (v2f){hn[2 * p], hn[2 * p + 1]} * rroot[p];
  h_out[n * 64 + lane] = fmaxf(rbias + rtv.x + rtv.y + acc / fmaxf(deg, 1.f), 0.f);
}

// ---------------- gated pooling, phase 1: 320 blocks ------------------------
__global__ __launch_bounds__(256) void pool1_kernel(
    const float* __restrict__ h4, const int* __restrict__ ct,
    float* __restrict__ pooled, float* __restrict__ pcnt) {
  __shared__ float ss[4][64];
  __shared__ float sc[4];
  int b = blockIdx.x / 20, c = blockIdx.x % 20;
  int base = b * (NN / NBATCH) + c * 64;
  int o = threadIdx.x & 63, sub = threadIdx.x >> 6;
  float sum = 0.f, cnt = 0.f;
  for (int j = sub; j < 64; j += 4) {
    int n = base + j;
    if (ct[n] == 1) { sum += h4[n * 64 + o]; cnt += 1.f; }
  }
  ss[sub][o] = sum;
  if (o == 0) sc[sub] = cnt;
  __syncthreads();
  if (threadIdx.x < 64) {
    float tot = ss[0][o] + ss[1][o] + ss[2][o] + ss[3][o];
    unsafeAtomicAdd(&pooled[b * 64 + o], tot);
    if (o == 0) unsafeAtomicAdd(&pcnt[b], sc[0] + sc[1] + sc[2] + sc[3]);
  }
}

// ---------------- pooling phase 2 + classifier + sigmoid (1 block) ----------
__global__ __launch_bounds__(1024) void pool2_kernel(
    const float* __restrict__ pooled, const float* __restrict__ pcnt,
    const float* __restrict__ clf_w, const float* __restrict__ clf_b,
    float* __restrict__ out) {
  int b = threadIdx.x >> 6, o = threadIdx.x & 63;
  float c = pcnt[b];
  float v = (pooled[b * 64 + o] / fmaxf(c, 1.f)) * clf_w[o];
#pragma unroll
  for (int d = 32; d; d >>= 1) v += __shfl_down(v, d);
  if (o == 0) out[b] = 1.f / (1.f + expf(-(v + clf_b[0])));
}

// ---------------------------------------------------------------------------
extern "C" void kernel_launch(void* const* d_in, const int* in_sizes, int n_in,
                              void* d_out, int out_size, void* d_ws, size_t ws_size,
                              hipStream_t stream) {
  (void)in_sizes; (void)n_in; (void)out_size; (void)ws_size;
  const float* x     = (const float*)d_in[0];
  const int*   eidx  = (const int*)d_in[1];
  const int*   src   = eidx;
  const int*   dst   = eidx + NE;
  const int*   etype = (const int*)d_in[2];
  const float* eattr = (const float*)d_in[3];
  const int*   ct    = (const int*)d_in[4];
  const float *emb[4], *wh[4], *bh[4], *wg[4], *bg[4], *root[4], *bias[4];
  for (int l = 0; l < 4; l++) {
    int b0 = 6 + 7 * l;
    emb[l]  = (const float*)d_in[b0 + 0];
    wh[l]   = (const float*)d_in[b0 + 1];
    bh[l]   = (const float*)d_in[b0 + 2];
    wg[l]   = (const float*)d_in[b0 + 3];
    bg[l]   = (const float*)d_in[b0 + 4];
    root[l] = (const float*)d_in[b0 + 5];
    bias[l] = (const float*)d_in[b0 + 6];
  }
  const float* clf_w = (const float*)d_in[34];
  const float* clf_b = (const float*)d_in[35];
  float* outp = (float*)d_out;

  // workspace layout (floats), ~11.9 MB
  float* ws  = (float*)d_ws;
  int*    off    = (int*)ws;                      // NN+1 (pad 20484)
  float4* es     = (float4*)(ws + 20484);         // NE float4
  float*  hA     = ws + 20484 + 4 * NE;           // 8N
  float*  hB     = hA + 8 * NN;                   // 8N
  float*  h4     = hB + 8 * NN;                   // 64N
  float*  pooled = h4 + 64 * NN;                  // 16*64
  float*  pcnt   = pooled + 16 * 64;              // 16
  int*    cnt    = (int*)h4;                      // alias (dead until L4)
  int*    cur    = cnt + NN;                      // alias

  // ---- build CSR by dst (graph identical across all 4 layers) ----
  hipMemsetAsync(cnt, 0, NN * sizeof(int), stream);
  hipMemsetAsync(pooled, 0, (16 * 64 + 16) * sizeof(float), stream);
  hist_kernel<<<NE / 256, 256, 0, stream>>>(dst, cnt);
  scan_kernel<<<1, 1024, 0, stream>>>(cnt, off, cur);
  scatter_kernel<<<NE / 256, 256, 0, stream>>>(src, dst, etype, eattr, cur, es);

  // ---- 4 fused layers ----
  layer_small16<<<2560, 256, 0, stream>>>(off, es, x,
      emb[0], wh[0], bh[0], wg[0], bg[0], root[0], bias[0], hA);
  layer_small8<<<1280, 256, 0, stream>>>(off, es, hA,
      emb[1], wh[1], bh[1], wg[1], bg[1], root[1], bias[1], hB);
  layer_small8<<<1280, 256, 0, stream>>>(off, es, hB,
      emb[2], wh[2], bh[2], wg[2], bg[2], root[2], bias[2], hA);
  layer_l4<<<5120, 256, 0, stream>>>(off, es, hA,
      emb[3], wh[3], bh[3], wg[3], bg[3], root[3], bias[3], h4);

  // ---- pooling + classifier + sigmoid ----
  pool1_kernel<<<320, 256, 0, stream>>>(h4, ct, pooled, pcnt);
  pool2_kernel<<<1, 1024, 0, stream>>>(pooled, pcnt, clf_w, clf_b, outp);
}